// Round 2
// baseline (207.253 us; speedup 1.0000x reference)
//
#include <hip/hip_runtime.h>
#include <hip/hip_bf16.h>

// Problem shapes (fixed by setup_inputs):
//   count_logits    : (16, 21)           fp32   -> d_in[0], 336
//   pred_heatmaps   : (16,20,17,64,64)   fp32   -> d_in[1], 22282240
//   pred_conf_logits: (16, 20)           fp32   -> d_in[2], 320
//   gt_heatmaps     : (16,20,17,64,64)   fp32   -> d_in[3], 22282240
//   count           : (16,)              int32  -> d_in[4], 16
//   mask            : (16, 20)           int32  -> d_in[5], 320
// Output: scalar total loss (fp32), out_size == 1.

#define B_      16
#define P_      20
#define NBP     (B_ * P_)          // 320 slices
#define KHW     (17 * 64 * 64)     // 69632 floats per slice
#define KHW4    (KHW / 4)          // 17408 float4 per slice
#define CHUNKS  17                 // blocks per slice; 17 * 256 * 4 = 17408 float4
#define NPART   (NBP * CHUNKS)     // 5440 partials
#define NTHREADS 256

#define PEAK_THRESH 0.2f
#define PEAK_WEIGHT 5.0f

__device__ __forceinline__ float wdiff4(float4 p, float4 g) {
    float d, w, a = 0.0f;
    d = p.x - g.x; w = (g.x > PEAK_THRESH) ? PEAK_WEIGHT : 1.0f; a = fmaf(d * d, w, a);
    d = p.y - g.y; w = (g.y > PEAK_THRESH) ? PEAK_WEIGHT : 1.0f; a = fmaf(d * d, w, a);
    d = p.z - g.z; w = (g.z > PEAK_THRESH) ? PEAK_WEIGHT : 1.0f; a = fmaf(d * d, w, a);
    d = p.w - g.w; w = (g.w > PEAK_THRESH) ? PEAK_WEIGHT : 1.0f; a = fmaf(d * d, w, a);
    return a;
}

__global__ __launch_bounds__(NTHREADS)
void hm_partial_kernel(const float4* __restrict__ pred,
                       const float4* __restrict__ gt,
                       const int*    __restrict__ mask,
                       float*        __restrict__ partial) {
    const int s    = blockIdx.y;                      // slice 0..319
    const int pidx = s * CHUNKS + blockIdx.x;
    if (mask[s] == 0) {                               // block-uniform early exit
        if (threadIdx.x == 0) partial[pidx] = 0.0f;   // d_ws is poisoned -> must zero
        return;
    }
    const int base = s * KHW4 + blockIdx.x * (NTHREADS * 4) + threadIdx.x;

    // 4 independent float4 pairs per thread (128 B), full load ILP, no loop
    const float4 p0 = pred[base];
    const float4 p1 = pred[base + 256];
    const float4 p2 = pred[base + 512];
    const float4 p3 = pred[base + 768];
    const float4 g0 = gt[base];
    const float4 g1 = gt[base + 256];
    const float4 g2 = gt[base + 512];
    const float4 g3 = gt[base + 768];

    float acc = (wdiff4(p0, g0) + wdiff4(p1, g1)) + (wdiff4(p2, g2) + wdiff4(p3, g3));

    // wave reduce (width 64)
    #pragma unroll
    for (int off = 32; off > 0; off >>= 1) acc += __shfl_down(acc, off);

    __shared__ float sm[NTHREADS / 64];
    if ((threadIdx.x & 63) == 0) sm[threadIdx.x >> 6] = acc;
    __syncthreads();
    if (threadIdx.x == 0) {
        float t = (sm[0] + sm[1]) + (sm[2] + sm[3]);
        partial[pidx] = t;
    }
}

__global__ __launch_bounds__(64)
void finalize_kernel(const float* __restrict__ partial,
                     const float* __restrict__ count_logits,
                     const int*   __restrict__ count,
                     const float* __restrict__ conf_logits,
                     const int*   __restrict__ mask,
                     float*       __restrict__ out) {
    const int lane = threadIdx.x;  // 64 threads, one wave

    // 1) heatmap diff sum over block partials
    float ds = 0.0f;
    for (int i = lane; i < NPART; i += 64) ds += partial[i];

    // 2) mask sum + focal loss over the 320 conf logits
    float ms = 0.0f, fs = 0.0f;
    for (int i = lane; i < NBP; i += 64) {
        const float t = (float)mask[i];
        ms += t;
        const float l   = conf_logits[i];
        const float bce = fmaxf(l, 0.0f) - l * t + log1pf(expf(-fabsf(l)));
        const float pt  = expf(-bce);
        const float om  = 1.0f - pt;
        fs += om * om * bce;     // gamma = 2
    }

    // 3) count cross-entropy: lane b < 16 handles row b (21 logits)
    float ce = 0.0f;
    if (lane < B_) {
        const float* row = count_logits + lane * (P_ + 1);
        float mx = row[0];
        #pragma unroll
        for (int j = 1; j < P_ + 1; ++j) mx = fmaxf(mx, row[j]);
        float se = 0.0f;
        #pragma unroll
        for (int j = 0; j < P_ + 1; ++j) se += expf(row[j] - mx);
        const float lse = mx + logf(se);
        ce = -(row[count[lane]] - lse);
    }

    // wave reduce all four
    #pragma unroll
    for (int off = 32; off > 0; off >>= 1) {
        ds += __shfl_down(ds, off);
        ms += __shfl_down(ms, off);
        fs += __shfl_down(fs, off);
        ce += __shfl_down(ce, off);
    }

    if (lane == 0) {
        const float loss_count = ce / (float)B_;
        const float loss_conf  = fs / (float)NBP;
        const float hm         = ds / (ms * (float)KHW + 1e-6f);
        const float loss_hm    = (ms > 0.0f) ? hm : 0.0f;
        out[0] = 1.0f * loss_count + 10.0f * loss_hm + 1.5f * loss_conf;
    }
}

extern "C" void kernel_launch(void* const* d_in, const int* in_sizes, int n_in,
                              void* d_out, int out_size, void* d_ws, size_t ws_size,
                              hipStream_t stream) {
    const float* count_logits = (const float*)d_in[0];
    const float* pred_hm      = (const float*)d_in[1];
    const float* conf_logits  = (const float*)d_in[2];
    const float* gt_hm        = (const float*)d_in[3];
    const int*   count        = (const int*)d_in[4];
    const int*   mask         = (const int*)d_in[5];
    float*       out          = (float*)d_out;
    float*       partial      = (float*)d_ws;   // NPART floats

    dim3 grid(CHUNKS, NBP);
    hm_partial_kernel<<<grid, NTHREADS, 0, stream>>>(
        (const float4*)pred_hm, (const float4*)gt_hm, mask, partial);

    finalize_kernel<<<1, 64, 0, stream>>>(
        partial, count_logits, count, conf_logits, mask, out);
}